// Round 6
// baseline (741.976 us; speedup 1.0000x reference)
//
#include <hip/hip_runtime.h>

#define U_N 100000
#define I_N 50000
#define D_N 128
#define B_N 4
#define E_N 500000
#define NEDGE (B_N * E_N)            // 2,000,000
#define NKEYU (4 * U_N)              // keys u*4+b
#define NKEYS (NKEYU + 4 * I_N)      // 600,000
#define NMEMB (2 * NEDGE)            // 4,000,000
#define SCHUNK 2048
#define SNBLK ((NKEYS + SCHUNK - 1) / SCHUNK)   // 293
#define TBI ((I_N + 31) / 32)        // transform blocks (item side)
#define TBU ((U_N + 31) / 32)        // transform blocks (user side)

// ---------------------------------------------------------------------------
// Fast zero of offs[NKEYS+1] (replaces pathologically slow rocclr fill).
// ---------------------------------------------------------------------------
__global__ __launch_bounds__(256) void zero_kernel(int4* __restrict__ p, int n4)
{
    int t = blockIdx.x * 256 + threadIdx.x;
    if (t < n4) p[t] = make_int4(0, 0, 0, 0);
}

// ---------------------------------------------------------------------------
// Fused transforms: tA = item_emb @ u_w, tB = user_emb @ i_w, one dispatch.
// ---------------------------------------------------------------------------
__global__ __launch_bounds__(256) void transform2_kernel(
    const float* __restrict__ item_emb, const float* __restrict__ user_emb,
    const float* __restrict__ u_w, const float* __restrict__ i_w,
    float* __restrict__ tA, float* __restrict__ tB)
{
    const float* X; const float* W; float* Y; int N; int blk;
    if (blockIdx.x < TBI) { X = item_emb; W = u_w; Y = tA; N = I_N; blk = blockIdx.x; }
    else                  { X = user_emb; W = i_w; Y = tB; N = U_N; blk = blockIdx.x - TBI; }

    __shared__ float wlds[D_N][D_N];
    for (int idx = threadIdx.x; idx < D_N * D_N / 4; idx += 256)
        reinterpret_cast<float4*>(&wlds[0][0])[idx] =
            reinterpret_cast<const float4*>(W)[idx];
    __syncthreads();

    int rr = threadIdx.x & 31;
    int cg = threadIdx.x >> 5;
    int c0 = cg * 16;
    int r  = blk * 32 + rr;
    bool valid = (r < N);
    int rc = valid ? r : (N - 1);
    const float* xrow = X + (size_t)rc * D_N;

    float4 acc[4];
    #pragma unroll
    for (int c = 0; c < 4; ++c) acc[c] = make_float4(0.f, 0.f, 0.f, 0.f);

    for (int k4 = 0; k4 < D_N / 4; ++k4) {
        float4 a = *reinterpret_cast<const float4*>(xrow + k4 * 4);
        #pragma unroll
        for (int kk = 0; kk < 4; ++kk) {
            float ak = (kk == 0) ? a.x : (kk == 1) ? a.y : (kk == 2) ? a.z : a.w;
            #pragma unroll
            for (int c = 0; c < 4; ++c) {
                const float4 wv = *reinterpret_cast<const float4*>(
                    &wlds[k4 * 4 + kk][c0 + c * 4]);
                acc[c].x += ak * wv.x;
                acc[c].y += ak * wv.y;
                acc[c].z += ak * wv.z;
                acc[c].w += ak * wv.w;
            }
        }
    }
    if (valid) {
        #pragma unroll
        for (int c = 0; c < 4; ++c)
            *reinterpret_cast<float4*>(Y + (size_t)r * D_N + c0 + c * 4) = acc[c];
    }
}

// ---------------------------------------------------------------------------
// Count + rank: one membership per thread; atomic return value = rank.
// ---------------------------------------------------------------------------
__global__ __launch_bounds__(256) void count_kernel(
    const int* __restrict__ eu, const int* __restrict__ ei,
    int* __restrict__ offs, int* __restrict__ rank_u, int* __restrict__ rank_i)
{
    int t = blockIdx.x * 256 + threadIdx.x;
    if (t >= NMEMB) return;
    if (t < NEDGE) {
        int e = t;
        int key = eu[e] * 4 + e / E_N;
        rank_u[e] = atomicAdd(&offs[key], 1);
    } else {
        int e = t - NEDGE;
        int key = NKEYU + ei[e] * 4 + e / E_N;
        rank_i[e] = atomicAdd(&offs[key], 1);
    }
}

// ---------------------------------------------------------------------------
// In-place hierarchical exclusive scan over offs[NKEYS].
// ---------------------------------------------------------------------------
__global__ __launch_bounds__(256) void scan1_kernel(
    int* __restrict__ offs, int* __restrict__ bsum)
{
    __shared__ int s[256];
    int base = blockIdx.x * SCHUNK + threadIdx.x * 8;
    int v[8]; int tsum = 0;
    #pragma unroll
    for (int j = 0; j < 8; ++j) {
        int idx = base + j;
        v[j] = (idx < NKEYS) ? offs[idx] : 0;
        tsum += v[j];
    }
    s[threadIdx.x] = tsum; __syncthreads();
    for (int off = 1; off < 256; off <<= 1) {
        int t = (threadIdx.x >= off) ? s[threadIdx.x - off] : 0;
        __syncthreads(); s[threadIdx.x] += t; __syncthreads();
    }
    int excl = s[threadIdx.x] - tsum;
    if (threadIdx.x == 255) bsum[blockIdx.x] = s[255];
    int run = excl;
    #pragma unroll
    for (int j = 0; j < 8; ++j) {
        int idx = base + j;
        if (idx < NKEYS) offs[idx] = run;
        run += v[j];
    }
}

__global__ __launch_bounds__(512) void scan2_kernel(int* __restrict__ bsum,
                                                    int* __restrict__ offs)
{
    __shared__ int s[512];
    int v = (threadIdx.x < SNBLK) ? bsum[threadIdx.x] : 0;
    s[threadIdx.x] = v; __syncthreads();
    for (int off = 1; off < 512; off <<= 1) {
        int t = (threadIdx.x >= off) ? s[threadIdx.x - off] : 0;
        __syncthreads(); s[threadIdx.x] += t; __syncthreads();
    }
    if (threadIdx.x < SNBLK) bsum[threadIdx.x] = s[threadIdx.x] - v;
    if (threadIdx.x == 511) offs[NKEYS] = s[511];
}

__global__ __launch_bounds__(256) void scan3_kernel(int* __restrict__ offs,
                                                    const int* __restrict__ bsum)
{
    int add = bsum[blockIdx.x];
    int base = blockIdx.x * SCHUNK + threadIdx.x * 8;
    #pragma unroll
    for (int j = 0; j < 8; ++j) {
        int idx = base + j;
        if (idx < NKEYS) offs[idx] += add;
    }
}

// ---------------------------------------------------------------------------
// Atomic-free fill: pos = offs[key] + precomputed rank.
// ---------------------------------------------------------------------------
__global__ __launch_bounds__(256) void fill_kernel(
    const int* __restrict__ eu, const int* __restrict__ ei,
    const float* __restrict__ ew,
    const int* __restrict__ offs,
    const int* __restrict__ rank_u, const int* __restrict__ rank_i,
    int2* __restrict__ pairs)
{
    int t = blockIdx.x * 256 + threadIdx.x;
    if (t >= NMEMB) return;
    if (t < NEDGE) {
        int e = t;
        int b = e / E_N;
        int key = eu[e] * 4 + b;
        int pos = offs[key] + rank_u[e];
        pairs[pos] = make_int2(ei[e], __float_as_int(ew[e]));
    } else {
        int e = t - NEDGE;
        int b = e / E_N;
        int key = NKEYU + ei[e] * 4 + b;
        int pos = offs[key] + rank_i[e];
        pairs[pos] = make_int2(eu[e], __float_as_int(ew[e]));
    }
}

// ---------------------------------------------------------------------------
// Gather: one wave per destination row; lanes own 2 floats; 2x-unrolled.
// ---------------------------------------------------------------------------
__global__ __launch_bounds__(256) void gather_kernel(
    const float* __restrict__ T,
    const int2* __restrict__ pairs,
    const int* __restrict__ offs,
    float* __restrict__ single,       // [B][N][D]
    float* __restrict__ multi,        // [N][D]
    int N, int keybase, const float* __restrict__ alpha_p)
{
    int r = blockIdx.x * 4 + (threadIdx.x >> 6);
    if (r >= N) return;
    float alpha = alpha_p[0];
    int lane = threadIdx.x & 63;
    int d = lane * 2;
    int k0 = keybase + r * 4;
    int beg = offs[k0];
    float mx = 0.f, my = 0.f;
    #pragma unroll
    for (int b = 0; b < 4; ++b) {
        int end = offs[k0 + b + 1];
        float ax = 0.f, ay = 0.f;
        int p = beg;
        for (; p + 1 < end; p += 2) {
            int2 pr0 = pairs[p];
            int2 pr1 = pairs[p + 1];
            float2 v0 = *reinterpret_cast<const float2*>(T + (size_t)pr0.x * D_N + d);
            float2 v1 = *reinterpret_cast<const float2*>(T + (size_t)pr1.x * D_N + d);
            float w0 = __int_as_float(pr0.y);
            float w1 = __int_as_float(pr1.y);
            ax += w0 * v0.x + w1 * v1.x;
            ay += w0 * v0.y + w1 * v1.y;
        }
        if (p < end) {
            int2 pr = pairs[p];
            float w = __int_as_float(pr.y);
            float2 v = *reinterpret_cast<const float2*>(T + (size_t)pr.x * D_N + d);
            ax += w * v.x;
            ay += w * v.y;
        }
        mx += ax; my += ay;
        float2 o;
        o.x = ax >= 0.f ? ax : alpha * ax;
        o.y = ay >= 0.f ? ay : alpha * ay;
        *reinterpret_cast<float2*>(single + ((size_t)b * N + r) * D_N + d) = o;
        beg = end;
    }
    mx *= 0.25f; my *= 0.25f;
    float2 o;
    o.x = mx >= 0.f ? mx : alpha * mx;
    o.y = my >= 0.f ? my : alpha * my;
    *reinterpret_cast<float2*>(multi + (size_t)r * D_N + d) = o;
}

extern "C" void kernel_launch(void* const* d_in, const int* in_sizes, int n_in,
                              void* d_out, int out_size, void* d_ws, size_t ws_size,
                              hipStream_t stream) {
    const float* user_emb = (const float*)d_in[0];
    const float* item_emb = (const float*)d_in[1];
    const int*   eu       = (const int*)d_in[2];
    const int*   ei       = (const int*)d_in[3];
    const float* ew       = (const float*)d_in[4];
    const float* u_w      = (const float*)d_in[5];
    const float* i_w      = (const float*)d_in[6];
    const float* alpha    = (const float*)d_in[7];

    float* out      = (float*)d_out;
    float* multi_u  = out;                                      // [U][D]
    float* multi_i  = out + (size_t)U_N * D_N;                  // [I][D]
    float* single_u = out + (size_t)(U_N + I_N) * D_N;          // [B][U][D]
    float* single_i = single_u + (size_t)B_N * U_N * D_N;       // [B][I][D]

    // tB lives in multi_u's slot (consumed by gather_i, written by gather_u).
    float* tB = multi_u;                                        // 51.2 MB
    // ranks live in multi_i's slot (consumed by fill; gather_i writes after).
    int* rank_u = (int*)multi_i;                                // 8 MB
    int* rank_i = rank_u + NEDGE;                               // 8 MB

    // d_ws: offs | bsum | pairs | tA  (~60.1 MB)
    int*  offs  = (int*)d_ws;                                   // NKEYS+1 (+pad)
    int*  bsum  = offs + (NKEYS + 4);                           // 512
    int2* pairs = (int2*)((char*)d_ws + ((((NKEYS + 4 + 512) * 4) + 255) & ~255));
    float* tA   = (float*)(pairs + NMEMB);                      // [I][D] 25.6 MB

    // fast zero of offs[0..NKEYS] (NKEYS+4 ints, 16B-aligned, n4 vectors)
    int n4 = (NKEYS + 4) / 4;
    zero_kernel<<<(n4 + 255) / 256, 256, 0, stream>>>((int4*)offs, n4);

    transform2_kernel<<<TBI + TBU, 256, 0, stream>>>(item_emb, user_emb,
                                                     u_w, i_w, tA, tB);
    count_kernel<<<(NMEMB + 255) / 256, 256, 0, stream>>>(eu, ei, offs,
                                                          rank_u, rank_i);
    scan1_kernel<<<SNBLK, 256, 0, stream>>>(offs, bsum);
    scan2_kernel<<<1, 512, 0, stream>>>(bsum, offs);
    scan3_kernel<<<SNBLK, 256, 0, stream>>>(offs, bsum);
    fill_kernel<<<(NMEMB + 255) / 256, 256, 0, stream>>>(eu, ei, ew, offs,
                                                         rank_u, rank_i, pairs);

    // i-side first: it reads tB (= multi_u slot, written by gather_u).
    gather_kernel<<<(I_N + 3) / 4, 256, 0, stream>>>(
        tB, pairs, offs, single_i, multi_i, I_N, NKEYU, alpha);
    gather_kernel<<<(U_N + 3) / 4, 256, 0, stream>>>(
        tA, pairs, offs, single_u, multi_u, U_N, 0, alpha);
}

// Round 8
// 674.251 us; speedup vs baseline: 1.1004x; 1.1004x over previous
//
#include <hip/hip_runtime.h>

#define U_N 100000
#define I_N 50000
#define D_N 128
#define B_N 4
#define E_N 500000
#define NEDGE (B_N * E_N)            // 2,000,000
#define NKEYU (4 * U_N)              // keys u*4+b
#define NKEYS (NKEYU + 4 * I_N)      // 600,000
#define NMEMB (2 * NEDGE)            // 4,000,000
#define SCHUNK 2048
#define SNBLK ((NKEYS + SCHUNK - 1) / SCHUNK)   // 293
#define TBI ((I_N + 31) / 32)        // transform blocks (item side)
#define TBU ((U_N + 31) / 32)        // transform blocks (user side)

typedef float f32x2 __attribute__((ext_vector_type(2)));

// ---------------------------------------------------------------------------
// Fast zero of offs[].
// ---------------------------------------------------------------------------
__global__ __launch_bounds__(256) void zero_kernel(int4* __restrict__ p, int n4)
{
    int t = blockIdx.x * 256 + threadIdx.x;
    if (t < n4) p[t] = make_int4(0, 0, 0, 0);
}

// ---------------------------------------------------------------------------
// Fused transforms: tA = item_emb @ u_w, tB = user_emb @ i_w, one dispatch.
// ---------------------------------------------------------------------------
__global__ __launch_bounds__(256) void transform2_kernel(
    const float* __restrict__ item_emb, const float* __restrict__ user_emb,
    const float* __restrict__ u_w, const float* __restrict__ i_w,
    float* __restrict__ tA, float* __restrict__ tB)
{
    const float* X; const float* W; float* Y; int N; int blk;
    if (blockIdx.x < TBI) { X = item_emb; W = u_w; Y = tA; N = I_N; blk = blockIdx.x; }
    else                  { X = user_emb; W = i_w; Y = tB; N = U_N; blk = blockIdx.x - TBI; }

    __shared__ float wlds[D_N][D_N];
    for (int idx = threadIdx.x; idx < D_N * D_N / 4; idx += 256)
        reinterpret_cast<float4*>(&wlds[0][0])[idx] =
            reinterpret_cast<const float4*>(W)[idx];
    __syncthreads();

    int rr = threadIdx.x & 31;
    int cg = threadIdx.x >> 5;
    int c0 = cg * 16;
    int r  = blk * 32 + rr;
    bool valid = (r < N);
    int rc = valid ? r : (N - 1);
    const float* xrow = X + (size_t)rc * D_N;

    float4 acc[4];
    #pragma unroll
    for (int c = 0; c < 4; ++c) acc[c] = make_float4(0.f, 0.f, 0.f, 0.f);

    for (int k4 = 0; k4 < D_N / 4; ++k4) {
        float4 a = *reinterpret_cast<const float4*>(xrow + k4 * 4);
        #pragma unroll
        for (int kk = 0; kk < 4; ++kk) {
            float ak = (kk == 0) ? a.x : (kk == 1) ? a.y : (kk == 2) ? a.z : a.w;
            #pragma unroll
            for (int c = 0; c < 4; ++c) {
                const float4 wv = *reinterpret_cast<const float4*>(
                    &wlds[k4 * 4 + kk][c0 + c * 4]);
                acc[c].x += ak * wv.x;
                acc[c].y += ak * wv.y;
                acc[c].z += ak * wv.z;
                acc[c].w += ak * wv.w;
            }
        }
    }
    if (valid) {
        #pragma unroll
        for (int c = 0; c < 4; ++c)
            *reinterpret_cast<float4*>(Y + (size_t)r * D_N + c0 + c * 4) = acc[c];
    }
}

// ---------------------------------------------------------------------------
// Count + rank: one membership per thread; atomic return value = rank.
// ---------------------------------------------------------------------------
__global__ __launch_bounds__(256) void count_kernel(
    const int* __restrict__ eu, const int* __restrict__ ei,
    int* __restrict__ offs, int* __restrict__ rank_u, int* __restrict__ rank_i)
{
    int t = blockIdx.x * 256 + threadIdx.x;
    if (t >= NMEMB) return;
    if (t < NEDGE) {
        int e = t;
        int key = eu[e] * 4 + e / E_N;
        rank_u[e] = atomicAdd(&offs[key], 1);
    } else {
        int e = t - NEDGE;
        int key = NKEYU + ei[e] * 4 + e / E_N;
        rank_i[e] = atomicAdd(&offs[key], 1);
    }
}

// ---------------------------------------------------------------------------
// In-place hierarchical exclusive scan over offs[NKEYS].
// ---------------------------------------------------------------------------
__global__ __launch_bounds__(256) void scan1_kernel(
    int* __restrict__ offs, int* __restrict__ bsum)
{
    __shared__ int s[256];
    int base = blockIdx.x * SCHUNK + threadIdx.x * 8;
    int v[8]; int tsum = 0;
    #pragma unroll
    for (int j = 0; j < 8; ++j) {
        int idx = base + j;
        v[j] = (idx < NKEYS) ? offs[idx] : 0;
        tsum += v[j];
    }
    s[threadIdx.x] = tsum; __syncthreads();
    for (int off = 1; off < 256; off <<= 1) {
        int t = (threadIdx.x >= off) ? s[threadIdx.x - off] : 0;
        __syncthreads(); s[threadIdx.x] += t; __syncthreads();
    }
    int excl = s[threadIdx.x] - tsum;
    if (threadIdx.x == 255) bsum[blockIdx.x] = s[255];
    int run = excl;
    #pragma unroll
    for (int j = 0; j < 8; ++j) {
        int idx = base + j;
        if (idx < NKEYS) offs[idx] = run;
        run += v[j];
    }
}

__global__ __launch_bounds__(512) void scan2_kernel(int* __restrict__ bsum,
                                                    int* __restrict__ offs)
{
    __shared__ int s[512];
    int v = (threadIdx.x < SNBLK) ? bsum[threadIdx.x] : 0;
    s[threadIdx.x] = v; __syncthreads();
    for (int off = 1; off < 512; off <<= 1) {
        int t = (threadIdx.x >= off) ? s[threadIdx.x - off] : 0;
        __syncthreads(); s[threadIdx.x] += t; __syncthreads();
    }
    if (threadIdx.x < SNBLK) bsum[threadIdx.x] = s[threadIdx.x] - v;
    if (threadIdx.x == 511) offs[NKEYS] = s[511];
}

__global__ __launch_bounds__(256) void scan3_kernel(int* __restrict__ offs,
                                                    const int* __restrict__ bsum)
{
    int add = bsum[blockIdx.x];
    int base = blockIdx.x * SCHUNK + threadIdx.x * 8;
    #pragma unroll
    for (int j = 0; j < 8; ++j) {
        int idx = base + j;
        if (idx < NKEYS) offs[idx] += add;
    }
}

// ---------------------------------------------------------------------------
// Atomic-free fill: pos = offs[key] + precomputed rank.
// ---------------------------------------------------------------------------
__global__ __launch_bounds__(256) void fill_kernel(
    const int* __restrict__ eu, const int* __restrict__ ei,
    const float* __restrict__ ew,
    const int* __restrict__ offs,
    const int* __restrict__ rank_u, const int* __restrict__ rank_i,
    int2* __restrict__ pairs)
{
    int t = blockIdx.x * 256 + threadIdx.x;
    if (t >= NMEMB) return;
    if (t < NEDGE) {
        int e = t;
        int b = e / E_N;
        int key = eu[e] * 4 + b;
        int pos = offs[key] + rank_u[e];
        pairs[pos] = make_int2(ei[e], __float_as_int(ew[e]));
    } else {
        int e = t - NEDGE;
        int b = e / E_N;
        int key = NKEYU + ei[e] * 4 + b;
        int pos = offs[key] + rank_i[e];
        pairs[pos] = make_int2(eu[e], __float_as_int(ew[e]));
    }
}

// ---------------------------------------------------------------------------
// Fused gather (both sides, one dispatch): one wave per destination row.
// Lanes own 2 floats. 4x-unrolled membership loop. Nontemporal output
// stores keep tA/tB resident in L2.
// ---------------------------------------------------------------------------
__global__ __launch_bounds__(256) void gather_kernel(
    const float* __restrict__ tA, const float* __restrict__ tB,
    const int2* __restrict__ pairs, const int* __restrict__ offs,
    float* __restrict__ single_u, float* __restrict__ multi_u,
    float* __restrict__ single_i, float* __restrict__ multi_i,
    const float* __restrict__ alpha_p)
{
    int rg = blockIdx.x * 4 + (threadIdx.x >> 6);
    if (rg >= U_N + I_N) return;
    bool uside = rg < U_N;
    int r = uside ? rg : rg - U_N;
    const float* T = uside ? tA : tB;
    float* single  = uside ? single_u : single_i;
    float* multi   = uside ? multi_u : multi_i;
    int N  = uside ? U_N : I_N;
    int k0 = uside ? r * 4 : NKEYU + r * 4;

    float alpha = alpha_p[0];
    int lane = threadIdx.x & 63;
    int d = lane * 2;

    int beg = offs[k0];
    float mx = 0.f, my = 0.f;
    #pragma unroll
    for (int b = 0; b < 4; ++b) {
        int end = offs[k0 + b + 1];
        float ax = 0.f, ay = 0.f;
        int p = beg;
        for (; p + 3 < end; p += 4) {
            int2 q0 = pairs[p];
            int2 q1 = pairs[p + 1];
            int2 q2 = pairs[p + 2];
            int2 q3 = pairs[p + 3];
            float2 v0 = *reinterpret_cast<const float2*>(T + (size_t)q0.x * D_N + d);
            float2 v1 = *reinterpret_cast<const float2*>(T + (size_t)q1.x * D_N + d);
            float2 v2 = *reinterpret_cast<const float2*>(T + (size_t)q2.x * D_N + d);
            float2 v3 = *reinterpret_cast<const float2*>(T + (size_t)q3.x * D_N + d);
            float w0 = __int_as_float(q0.y), w1 = __int_as_float(q1.y);
            float w2 = __int_as_float(q2.y), w3 = __int_as_float(q3.y);
            ax += w0 * v0.x + w1 * v1.x + w2 * v2.x + w3 * v3.x;
            ay += w0 * v0.y + w1 * v1.y + w2 * v2.y + w3 * v3.y;
        }
        for (; p < end; ++p) {
            int2 q = pairs[p];
            float w = __int_as_float(q.y);
            float2 v = *reinterpret_cast<const float2*>(T + (size_t)q.x * D_N + d);
            ax += w * v.x;
            ay += w * v.y;
        }
        mx += ax; my += ay;
        f32x2 o;
        o.x = ax >= 0.f ? ax : alpha * ax;
        o.y = ay >= 0.f ? ay : alpha * ay;
        __builtin_nontemporal_store(o,
            reinterpret_cast<f32x2*>(single + ((size_t)b * N + r) * D_N + d));
        beg = end;
    }
    mx *= 0.25f; my *= 0.25f;
    f32x2 o;
    o.x = mx >= 0.f ? mx : alpha * mx;
    o.y = my >= 0.f ? my : alpha * my;
    __builtin_nontemporal_store(o,
        reinterpret_cast<f32x2*>(multi + (size_t)r * D_N + d));
}

extern "C" void kernel_launch(void* const* d_in, const int* in_sizes, int n_in,
                              void* d_out, int out_size, void* d_ws, size_t ws_size,
                              hipStream_t stream) {
    const float* user_emb = (const float*)d_in[0];
    const float* item_emb = (const float*)d_in[1];
    const int*   eu       = (const int*)d_in[2];
    const int*   ei       = (const int*)d_in[3];
    const float* ew       = (const float*)d_in[4];
    const float* u_w      = (const float*)d_in[5];
    const float* i_w      = (const float*)d_in[6];
    const float* alpha    = (const float*)d_in[7];

    float* out      = (float*)d_out;
    float* multi_u  = out;                                      // [U][D]
    float* multi_i  = out + (size_t)U_N * D_N;                  // [I][D]
    float* single_u = out + (size_t)(U_N + I_N) * D_N;          // [B][U][D]
    float* single_i = single_u + (size_t)B_N * U_N * D_N;       // [B][I][D]

    // ranks live in multi_i's slot (consumed by fill; gather writes after).
    int* rank_u = (int*)multi_i;                                // 8 MB
    int* rank_i = rank_u + NEDGE;                               // 8 MB

    // d_ws: offs | bsum | pairs | tA | tB  (~111.3 MB)
    int*  offs  = (int*)d_ws;                                   // NKEYS+4
    int*  bsum  = offs + (NKEYS + 4);                           // 512
    int2* pairs = (int2*)((char*)d_ws + ((((NKEYS + 4 + 512) * 4) + 255) & ~255));
    float* tA   = (float*)(pairs + NMEMB);                      // [I][D] 25.6 MB
    float* tB   = tA + (size_t)I_N * D_N;                       // [U][D] 51.2 MB

    int n4 = (NKEYS + 4) / 4;
    zero_kernel<<<(n4 + 255) / 256, 256, 0, stream>>>((int4*)offs, n4);

    transform2_kernel<<<TBI + TBU, 256, 0, stream>>>(item_emb, user_emb,
                                                     u_w, i_w, tA, tB);
    count_kernel<<<(NMEMB + 255) / 256, 256, 0, stream>>>(eu, ei, offs,
                                                          rank_u, rank_i);
    scan1_kernel<<<SNBLK, 256, 0, stream>>>(offs, bsum);
    scan2_kernel<<<1, 512, 0, stream>>>(bsum, offs);
    scan3_kernel<<<SNBLK, 256, 0, stream>>>(offs, bsum);
    fill_kernel<<<(NMEMB + 255) / 256, 256, 0, stream>>>(eu, ei, ew, offs,
                                                         rank_u, rank_i, pairs);

    gather_kernel<<<(U_N + I_N + 3) / 4, 256, 0, stream>>>(
        tA, tB, pairs, offs,
        single_u, multi_u, single_i, multi_i, alpha);
}